// Round 5
// baseline (71.436 us; speedup 1.0000x reference)
//
#include <hip/hip_runtime.h>

#define N_GENERA 4096
#define N_RANKS 6
#define N_GROUPS 256
#define NCH 7                          // 6 ranks + identity channel
#define SEG_SZ (N_RANKS * N_GROUPS)    // 1536
#define EXT_SZ (SEG_SZ + N_GENERA)     // 5632 float2; +1 zero-pad slot
#define NF (N_GENERA * NCH)            // 28672 output floats per b
#define NF4 (NF / 4)                   // 7168 float4 per b
#define MAXP 48                        // padded idx row length (Poisson(16) max ~45)
#define PAD_I N_GENERA                 // pad genus index -> Fl2[4096] == ext2[5632] == 0

typedef float f32x4 __attribute__((ext_vector_type(4)));

// ws layout:
//   idx  [6][4096]    int   @ 0        (96 KB)   raw CSR (cold fallback)
//   offs [6][260]     int   @ 98304
//   sidx [NF]         short @ 104704   (56 KB)   output-float -> ext[] index
//   perm [1536]       int   @ 162048   length-sorted slot -> (r,g)
//   lenT [1536]       int   @ 168192   list length per sorted slot
//   idxP [1536][48]   int   @ 174336   (288 KB)  padded per-slot index rows
#define WS_IDX_OFF   0
#define WS_OFFS_OFF  98304
#define WS_SIDX_OFF  104704
#define WS_PERM_OFF  162048
#define WS_LENT_OFF  168192
#define WS_IDXP_OFF  174336

__device__ __forceinline__ int imin(int a, int b) { return a < b ? a : b; }

// ---------- Kernel 0: prep1 = CSR (0..5) + sidx (6..117) + perm/lenT (118) ----------
__global__ __launch_bounds__(256) void prep1_kernel(
    const int* __restrict__ labels,
    int* __restrict__ idx,      // [R][N_GENERA]
    int* __restrict__ offs,     // [R][260]
    short* __restrict__ sidx,   // [NF]
    int* __restrict__ perm,     // [1536]
    int* __restrict__ lenT)     // [1536]
{
    const int t = threadIdx.x;

    if (blockIdx.x < N_RANKS) {
        const int r = blockIdx.x;
        const int* __restrict__ lab = labels + r * N_GENERA;

        __shared__ int cnt[N_GROUPS];
        __shared__ int scan[N_GROUPS];
        __shared__ int cur[N_GROUPS];

        cnt[t] = 0;
        __syncthreads();
        for (int i = t; i < N_GENERA; i += 256)
            atomicAdd(&cnt[lab[i]], 1);
        __syncthreads();

        int v = cnt[t];
        scan[t] = v;
        __syncthreads();
        #pragma unroll
        for (int s = 1; s < 256; s <<= 1) {
            int add = (t >= s) ? scan[t - s] : 0;
            __syncthreads();
            scan[t] += add;
            __syncthreads();
        }
        int start = scan[t] - v;          // exclusive prefix
        cur[t] = start;
        offs[r * 260 + t] = start;
        if (t == 0) offs[r * 260 + 256] = N_GENERA;
        __syncthreads();
        for (int i = t; i < N_GENERA; i += 256) {
            int p = atomicAdd(&cur[lab[i]], 1);
            idx[r * N_GENERA + p] = i;
        }
    } else if (blockIdx.x < N_RANKS + 112) {
        // sidx: output-float -> ext[]-index map (batch-independent)
        const int f = (blockIdx.x - N_RANKS) * 256 + t;   // < NF
        const int j = f / NCH;
        const int ch = f - j * NCH;
        int v;
        if (ch < N_RANKS)
            v = ch * N_GROUPS + labels[ch * N_GENERA + j];
        else
            v = SEG_SZ + j;               // identity channel -> F slot
        sidx[f] = (short)v;
    } else {
        // perm: count-sort the 1536 (r,g) items by descending count; waves of
        // adjacent sorted slots then have near-equal CSR list lengths.
        __shared__ int cnt[SEG_SZ];
        __shared__ int hist[64];
        __shared__ int base[64];
        __shared__ int cur[64];
        for (int i = t; i < SEG_SZ; i += 256) cnt[i] = 0;
        if (t < 64) { hist[t] = 0; cur[t] = 0; }
        __syncthreads();
        for (int r = 0; r < N_RANKS; ++r)
            for (int i = t; i < N_GENERA; i += 256)
                atomicAdd(&cnt[r * N_GROUPS + labels[r * N_GENERA + i]], 1);
        __syncthreads();
        for (int p = t; p < SEG_SZ; p += 256)
            atomicAdd(&hist[imin(cnt[p], 63)], 1);
        __syncthreads();
        if (t < 64) {
            int bsum = 0;
            for (int c = t + 1; c < 64; ++c) bsum += hist[c];
            base[t] = bsum;               // descending-count exclusive base
        }
        __syncthreads();
        for (int p = t; p < SEG_SZ; p += 256) {
            int c = imin(cnt[p], 63);
            int slot = base[c] + atomicAdd(&cur[c], 1);
            perm[slot] = p;
            lenT[slot] = cnt[p];
        }
    }
}

// ---------- Kernel 0b: prep2 = padded, 16B-aligned per-slot index rows ----------
__global__ __launch_bounds__(256) void prep2_kernel(
    const int* __restrict__ idx,
    const int* __restrict__ offs,
    const int* __restrict__ perm,
    int* __restrict__ idxP)           // [1536][MAXP]
{
    const int s = blockIdx.x * 256 + threadIdx.x;   // sorted slot < 1536
    const int p = perm[s];
    const int r = p >> 8;
    const int g = p & 255;
    const int beg = offs[r * 260 + g];
    const int e   = offs[r * 260 + g + 1];
    const int lm = imin(e - beg, MAXP);
    const int* __restrict__ ip = idx + r * N_GENERA + beg;
    int* __restrict__ row = idxP + s * MAXP;
    for (int k = 0; k < MAXP; ++k)
        row[k] = (k < lm) ? ip[k] : PAD_I;          // pad hits zeroed LDS slot
}

// ---------- Kernel 1: fused CSR-seg + gather, TWO batch rows per block ----------
// LDS ext2[] = { seg[1536] | Frow[4096] | zero-pad[1] } float2 (45.1 KB).
// Phase A: wave-balanced slots {t, 512+t, 1535-t} (L_A>=L_C>=L_B), padded
//          int4 index rows (fixed trips, no tail), 3 independent acc chains,
//          k=0 quads prefetched above the barrier.
// Phase B: coalesced short4 sidx read, 4 ds_read_b64 gathers, 2 contiguous
//          nontemporal float4 stores. Two barriers total.
__global__ __launch_bounds__(512) void fused_kernel(
    const float* __restrict__ F,
    const int* __restrict__ idx,
    const int* __restrict__ offs,
    const int* __restrict__ perm,
    const int* __restrict__ lenT,
    const int* __restrict__ idxP,
    const short* __restrict__ sidx,
    float* __restrict__ out)
{
    __shared__ float2 ext2[EXT_SZ + 1];
    const int b0 = blockIdx.x * 2;
    const int t = threadIdx.x;

    // stage 2 F rows pair-interleaved into ext2[SEG_SZ..)
    const f32x4* Fv0 = reinterpret_cast<const f32x4*>(F + (size_t)b0 * N_GENERA);
    const f32x4* Fv1 = reinterpret_cast<const f32x4*>(F + (size_t)(b0 + 1) * N_GENERA);
    f32x4* Flv = reinterpret_cast<f32x4*>(ext2 + SEG_SZ);
    #pragma unroll
    for (int k = 0; k < 2; ++k) {
        const f32x4 a = __builtin_nontemporal_load(Fv0 + t + k * 512);
        const f32x4 c = __builtin_nontemporal_load(Fv1 + t + k * 512);
        f32x4 lo, hi;
        lo[0] = a[0]; lo[1] = c[0]; lo[2] = a[1]; lo[3] = c[1];
        hi[0] = a[2]; hi[1] = c[2]; hi[2] = a[3]; hi[3] = c[3];
        Flv[2 * (t + k * 512)]     = lo;
        Flv[2 * (t + k * 512) + 1] = hi;
    }
    if (t == 0) { float2 z; z.x = 0.f; z.y = 0.f; ext2[EXT_SZ] = z; }  // pad slot

    // Phase A setup + prefetch (global, independent of LDS barrier)
    const int sA = t, sC = 512 + t, sB = 1535 - t;
    const int pA = perm[sA], pC = perm[sC], pB = perm[sB];
    const int LA = lenT[sA], LC = lenT[sC], LB = lenT[sB];
    const int4* __restrict__ qA = reinterpret_cast<const int4*>(idxP + sA * MAXP);
    const int4* __restrict__ qC = reinterpret_cast<const int4*>(idxP + sC * MAXP);
    const int4* __restrict__ qB = reinterpret_cast<const int4*>(idxP + sB * MAXP);
    const int4 xA0 = qA[0];
    const int4 xC0 = qC[0];
    const int4 xB0 = qB[0];
    const int nA = (imin(LA, MAXP) + 3) >> 2;   // nA >= nC >= nB by sort
    const int nC = (imin(LC, MAXP) + 3) >> 2;
    const int nB = (imin(LB, MAXP) + 3) >> 2;

    __syncthreads();

    const float2* __restrict__ Fl2 = ext2 + SEG_SZ;
    float2 aA; aA.x = 0.f; aA.y = 0.f;
    float2 aC = aA, aB = aA;

    #define ACC4(X, A)                                                        \
        {   float2 v0 = Fl2[(X).x], v1 = Fl2[(X).y];                          \
            float2 v2 = Fl2[(X).z], v3 = Fl2[(X).w];                          \
            (A).x += (v0.x + v1.x) + (v2.x + v3.x);                           \
            (A).y += (v0.y + v1.y) + (v2.y + v3.y); }

    int k = 0;
    if (nB > 0)      { ACC4(xA0, aA); ACC4(xC0, aC); ACC4(xB0, aB); k = 1; }
    else if (nC > 0) { ACC4(xA0, aA); ACC4(xC0, aC); k = 1; }
    else if (nA > 0) { ACC4(xA0, aA); k = 1; }
    for (; k < nB; ++k) { int4 x = qA[k], y = qC[k], z = qB[k];
                          ACC4(x, aA); ACC4(y, aC); ACC4(z, aB); }
    for (; k < nC; ++k) { int4 x = qA[k], y = qC[k];
                          ACC4(x, aA); ACC4(y, aC); }
    for (; k < nA; ++k) { int4 x = qA[k];
                          ACC4(x, aA); }

    // cold fallback for pathological list lengths (> MAXP)
    if (LA > MAXP || LC > MAXP || LB > MAXP) {
        #pragma unroll
        for (int m = 0; m < 3; ++m) {
            const int L = (m == 0) ? LA : (m == 1) ? LC : LB;
            if (L <= MAXP) continue;
            const int p = (m == 0) ? pA : (m == 1) ? pC : pB;
            float2* A = (m == 0) ? &aA : (m == 1) ? &aC : &aB;
            const int r = p >> 8, g = p & 255;
            const int beg = offs[r * 260 + g];
            const int* __restrict__ ip = idx + r * N_GENERA + beg;
            for (int k2 = MAXP; k2 < L; ++k2) {
                float2 v = Fl2[ip[k2]];
                A->x += v.x; A->y += v.y;
            }
        }
    }

    ext2[pA] = aA; ext2[pC] = aC; ext2[pB] = aB;   // seg region, disjoint from F
    __syncthreads();

    // Phase B: 14 output float4 per b per thread, lanes contiguous per store
    f32x4* __restrict__ op0 = reinterpret_cast<f32x4*>(out) + (size_t)b0 * NF4;
    f32x4* __restrict__ op1 = op0 + NF4;
    #pragma unroll
    for (int kk = 0; kk < 14; ++kk) {
        const int q = kk * 512 + t;
        short4 s4 = *reinterpret_cast<const short4*>(sidx + q * 4);
        float2 p0 = ext2[s4.x];
        float2 p1 = ext2[s4.y];
        float2 p2 = ext2[s4.z];
        float2 p3 = ext2[s4.w];
        f32x4 va, vb;
        va[0] = p0.x; va[1] = p1.x; va[2] = p2.x; va[3] = p3.x;
        vb[0] = p0.y; vb[1] = p1.y; vb[2] = p2.y; vb[3] = p3.y;
        __builtin_nontemporal_store(va, op0 + q);
        __builtin_nontemporal_store(vb, op1 + q);
    }
}

extern "C" void kernel_launch(void* const* d_in, const int* in_sizes, int n_in,
                              void* d_out, int out_size, void* d_ws, size_t ws_size,
                              hipStream_t stream) {
    const float* F      = (const float*)d_in[0];
    const int*   labels = (const int*)d_in[1];
    float*       out    = (float*)d_out;

    const int B = in_sizes[0] / N_GENERA;  // 1024
    char* ws = (char*)d_ws;
    int*   idx  = (int*)(ws + WS_IDX_OFF);
    int*   offs = (int*)(ws + WS_OFFS_OFF);
    short* sidx = (short*)(ws + WS_SIDX_OFF);
    int*   perm = (int*)(ws + WS_PERM_OFF);
    int*   lenT = (int*)(ws + WS_LENT_OFF);
    int*   idxP = (int*)(ws + WS_IDXP_OFF);

    prep1_kernel<<<dim3(N_RANKS + 112 + 1), dim3(256), 0, stream>>>(
        labels, idx, offs, sidx, perm, lenT);
    prep2_kernel<<<dim3(SEG_SZ / 256), dim3(256), 0, stream>>>(idx, offs, perm, idxP);
    fused_kernel<<<dim3(B / 2), dim3(512), 0, stream>>>(
        F, idx, offs, perm, lenT, idxP, sidx, out);
}

// Round 6
// 43.297 us; speedup vs baseline: 1.6499x; 1.6499x over previous
//
#include <hip/hip_runtime.h>

#define N_GENERA 4096
#define N_RANKS 6
#define N_GROUPS 256
#define NCH 7                         // 6 ranks + identity channel
#define SEG_SZ (N_RANKS * N_GROUPS)   // 1536
#define EXT_SZ (SEG_SZ + N_GENERA)    // 5632 pairs = 45 KB as float2
#define NF (N_GENERA * NCH)           // 28672 output floats per b
#define NF4 (NF / 4)                  // 7168 float4 per b

typedef float f32x4 __attribute__((ext_vector_type(4)));

// ws layout:
//   idx  [6][4096] int   @ 0        (96 KB)
//   offs [6][260]  int   @ 98304    (6.1 KB)
//   sidx [NF]      short @ 104704   (56 KB)
#define WS_IDX_OFF  0
#define WS_OFFS_OFF 98304
#define WS_SIDX_OFF 104704

// ---------- Kernel 0: prep = per-rank CSR (blocks 0..5) + sidx map (blocks 6..117) ----------
__global__ __launch_bounds__(256) void prep_kernel(
    const int* __restrict__ labels,
    int* __restrict__ idx,      // [R][N_GENERA]
    int* __restrict__ offs,     // [R][260]
    short* __restrict__ sidx)   // [NF]
{
    const int t = threadIdx.x;

    if (blockIdx.x < N_RANKS) {
        const int r = blockIdx.x;
        const int* __restrict__ lab = labels + r * N_GENERA;

        __shared__ int cnt[N_GROUPS];
        __shared__ int scan[N_GROUPS];
        __shared__ int cur[N_GROUPS];

        cnt[t] = 0;
        __syncthreads();
        for (int i = t; i < N_GENERA; i += 256)
            atomicAdd(&cnt[lab[i]], 1);   // int atomics, build-once: cheap enough
        __syncthreads();

        int v = cnt[t];
        scan[t] = v;
        __syncthreads();
        #pragma unroll
        for (int s = 1; s < 256; s <<= 1) {
            int add = (t >= s) ? scan[t - s] : 0;
            __syncthreads();
            scan[t] += add;
            __syncthreads();
        }
        int start = scan[t] - v;          // exclusive prefix
        cur[t] = start;
        offs[r * 260 + t] = start;
        if (t == 0) offs[r * 260 + 256] = N_GENERA;
        __syncthreads();
        for (int i = t; i < N_GENERA; i += 256) {
            int p = atomicAdd(&cur[lab[i]], 1);
            idx[r * N_GENERA + p] = i;
        }
    } else {
        // sidx: output-float -> ext[]-index map (batch-independent)
        const int f = (blockIdx.x - N_RANKS) * 256 + t;   // < NF
        const int j = f / NCH;
        const int ch = f - j * NCH;
        int v;
        if (ch < N_RANKS)
            v = ch * N_GROUPS + labels[ch * N_GENERA + j];
        else
            v = SEG_SZ + j;               // identity channel -> F slot
        sidx[f] = (short)v;
    }
}

// ---------- Kernel 1: fused CSR-seg + gather, TWO batch rows per block ----------
// LDS ext2[] = { seg[1536] | Frow[4096] } of float2 = {val_b0, val_b1} (45 KB).
// Amortizes every scattered LDS access across 2 batch rows: one ds_read_b64
// serves two output floats. sidx/CSR maps are batch-independent.
// Phase A: stage 2 F rows pair-interleaved; each thread serially sums its
//          3 CSR (rank,group) lists (both b's per ds_read_b64, no atomics).
// Phase B: coalesced short4 sidx read, 4 ds_read_b64 gathers, 2 contiguous
//          PLAIN float4 stores (one per b). NT removed: nt bypasses L2, and
//          1024 concurrent NT streams lose write aggregation (~3.4 TB/s vs
//          fills' 6.7-7.0 with plain stores). Two barriers total.
__global__ __launch_bounds__(512) void fused_kernel(
    const float* __restrict__ F,
    const int* __restrict__ idx,
    const int* __restrict__ offs,
    const short* __restrict__ sidx,
    float* __restrict__ out)
{
    __shared__ float2 ext2[EXT_SZ];
    const int b0 = blockIdx.x * 2;
    const int t = threadIdx.x;

    // zero seg region (1536 pairs = 3*512)
    const float2 z2 = {0.f, 0.f};
    ext2[t] = z2; ext2[t + 512] = z2; ext2[t + 1024] = z2;

    // stage 2 F rows pair-interleaved into ext2[SEG_SZ..)
    const f32x4* Fv0 = reinterpret_cast<const f32x4*>(F + (size_t)b0 * N_GENERA);
    const f32x4* Fv1 = reinterpret_cast<const f32x4*>(F + (size_t)(b0 + 1) * N_GENERA);
    f32x4* Flv = reinterpret_cast<f32x4*>(ext2 + SEG_SZ);
    #pragma unroll
    for (int k = 0; k < 2; ++k) {
        const f32x4 a = __builtin_nontemporal_load(Fv0 + t + k * 512);
        const f32x4 c = __builtin_nontemporal_load(Fv1 + t + k * 512);
        f32x4 lo, hi;
        lo[0] = a[0]; lo[1] = c[0]; lo[2] = a[1]; lo[3] = c[1];
        hi[0] = a[2]; hi[1] = c[2]; hi[2] = a[3]; hi[3] = c[3];
        Flv[2 * (t + k * 512)]     = lo;
        Flv[2 * (t + k * 512) + 1] = hi;
    }
    __syncthreads();

    // Phase A: CSR segment sums for both b's, 3 (r,g) items per thread
    const float2* __restrict__ Fl2 = ext2 + SEG_SZ;
    #pragma unroll
    for (int w = 0; w < 3; ++w) {
        const int item = t + w * 512;
        const int r = item >> 8;
        const int g = item & 255;
        const int e = offs[r * 260 + g + 1];   // g==255 -> offs[r][256]==4096
        int k = offs[r * 260 + g];
        const int* __restrict__ ip = idx + r * N_GENERA;
        float sa = 0.f, sb = 0.f;
        for (; k + 4 <= e; k += 4) {
            int i0 = ip[k], i1 = ip[k + 1], i2 = ip[k + 2], i3 = ip[k + 3];
            float2 v0 = Fl2[i0], v1 = Fl2[i1], v2 = Fl2[i2], v3 = Fl2[i3];
            sa += (v0.x + v1.x) + (v2.x + v3.x);
            sb += (v0.y + v1.y) + (v2.y + v3.y);
        }
        for (; k < e; ++k) {
            float2 v = Fl2[ip[k]];
            sa += v.x; sb += v.y;
        }
        float2 sp; sp.x = sa; sp.y = sb;
        ext2[item] = sp;   // seg region; disjoint from F region being read
    }
    __syncthreads();

    // Phase B: 14 output float4 per b per thread, lanes contiguous per store
    f32x4* __restrict__ op0 = reinterpret_cast<f32x4*>(out) + (size_t)b0 * NF4;
    f32x4* __restrict__ op1 = op0 + NF4;
    #pragma unroll
    for (int kk = 0; kk < 14; ++kk) {
        const int q = kk * 512 + t;
        short4 s4 = *reinterpret_cast<const short4*>(sidx + q * 4);
        float2 p0 = ext2[s4.x];
        float2 p1 = ext2[s4.y];
        float2 p2 = ext2[s4.z];
        float2 p3 = ext2[s4.w];
        f32x4 va, vb;
        va[0] = p0.x; va[1] = p1.x; va[2] = p2.x; va[3] = p3.x;
        vb[0] = p0.y; vb[1] = p1.y; vb[2] = p2.y; vb[3] = p3.y;
        op0[q] = va;    // plain stores: let L2 aggregate the write streams
        op1[q] = vb;
    }
}

extern "C" void kernel_launch(void* const* d_in, const int* in_sizes, int n_in,
                              void* d_out, int out_size, void* d_ws, size_t ws_size,
                              hipStream_t stream) {
    const float* F      = (const float*)d_in[0];
    const int*   labels = (const int*)d_in[1];
    float*       out    = (float*)d_out;

    const int B = in_sizes[0] / N_GENERA;  // 1024
    char* ws = (char*)d_ws;
    int*   idx  = (int*)(ws + WS_IDX_OFF);
    int*   offs = (int*)(ws + WS_OFFS_OFF);
    short* sidx = (short*)(ws + WS_SIDX_OFF);

    const int sidx_blocks = NF / 256;   // 112
    prep_kernel<<<dim3(N_RANKS + sidx_blocks), dim3(256), 0, stream>>>(labels, idx, offs, sidx);
    fused_kernel<<<dim3(B / 2), dim3(512), 0, stream>>>(F, idx, offs, sidx, out);
}